// Round 1
// 197.615 us; speedup vs baseline: 1.0051x; 1.0051x over previous
//
#include <hip/hip_runtime.h>
#include <hip/hip_bf16.h>
#include <math.h>

// Router: logits = x@W + b ; softmax; top-2 -> (idx-as-float, gate)
// x: [16384, 2048] f32, W: [2048, 64] f32, b: [64] f32
// out f32: [ntok*2] indices, then [ntok*2] gates.
//
// bf16 hi/lo split GEMM on MFMA (3 products; lo*lo dropped, ~1e-4 abs).
// Barrier-free K-loop, now 3-deep: each wave owns a private 3x4KB LDS
// ring buffer, streams x via global_load_lds(16B) with per-row rotated
// layout, W fragments are register-double-buffered, and the manual
// s_waitcnt immediates are exact per (fully unrolled) iteration.

#define DIM 2048
#define NE 64

typedef __attribute__((ext_vector_type(8))) short short8;
typedef __attribute__((ext_vector_type(4))) float floatx4;

__device__ __forceinline__ short bf16bits(float v) {
  __hip_bfloat16 h = __float2bfloat16(v);
  return *(short*)&h;
}
__device__ __forceinline__ float bf16tof(short s) {
  union { unsigned int u; float f; } c;
  c.u = ((unsigned int)(unsigned short)s) << 16;
  return c.f;
}

// ---- W fragment prep: wf[sg(64)][n(4)][plane(2)][lane(64)] = short8 ----
// B-frag 16x16x32: lane l holds B[k = sg*32 + (l>>4)*8 + j][e = n*16 + (l&15)]
__global__ void wprep_kernel(const float* __restrict__ W, short8* __restrict__ wf) {
  const int s = blockIdx.x >> 2, n = blockIdx.x & 3, l = threadIdx.x;
  const int d0 = s * 32 + (l >> 4) * 8;
  const int e = n * 16 + (l & 15);
  short8 vh, vl;
#pragma unroll
  for (int j = 0; j < 8; ++j) {
    float v = W[(size_t)(d0 + j) * NE + e];
    short h = bf16bits(v);
    vh[j] = h;
    vl[j] = bf16bits(v - bf16tof(h));
  }
  wf[(size_t)((s * 4 + n) * 2 + 0) * 64 + l] = vh;
  wf[(size_t)((s * 4 + n) * 2 + 1) * 64 + l] = vl;
}

__device__ __forceinline__ void async_copy16(const float* g, void* lds) {
  __builtin_amdgcn_global_load_lds(
      (const __attribute__((address_space(1))) unsigned int*)g,
      (__attribute__((address_space(3))) unsigned int*)lds, 16, 0, 0);
}

__global__ __launch_bounds__(256, 2) void router_main(
    const float* __restrict__ x, const short8* __restrict__ wf,
    const float* __restrict__ b, float* __restrict__ out, int ntok) {
  // main loop: wave kq uses smem + kq*12288 (3 x 4KB ring buffer) = 48 KB
  // epilogue: red[kq(4)][tok(32)][e stride 65] = 33280 B (reuses same smem)
  __shared__ alignas(16) char smem[49152];
  const int tid = threadIdx.x;
  const int lane = tid & 63;
  const int kq = tid >> 6;        // wave = K-quarter (512 d's)
  const int g = lane & 15, r4 = lane >> 4;
  const int tok0 = blockIdx.x * 32;

  char* mybuf = smem + kq * 12288;
  const float* xb = x + (size_t)tok0 * DIM + kq * 512;

  // chunk = 32 tok x 32 k (4 KB). LDS[row][slot G]: G = (kgroup4 + row) & 7
  // (rotation -> conflict-free ds_read_b128; DMA fetch stays 128B-contiguous
  //  per row). Instruction p covers rows p*8..p*8+7.
  auto issue = [&](int c, char* dst) {
    const float* gb = xb + c * 32;
#pragma unroll
    for (int p = 0; p < 4; ++p) {
      const int rr = p * 8 + (lane >> 3);
      const float* gp = gb + (size_t)rr * DIM + ((((lane & 7) - rr) & 7) << 2);
      async_copy16(gp, dst + p * 1024);
    }
  };

  // W fragments for one K-subgroup (32 d's): 8x 16B loads, L2-resident.
  const short8* wfbase = wf + (size_t)(kq * 16) * 8 * 64;
  auto loadWF = [&](int c, short8 (&Wh)[4], short8 (&Wl)[4]) {
    const short8* wp = wfbase + (size_t)c * 8 * 64;
#pragma unroll
    for (int n = 0; n < 4; ++n) {
      Wh[n] = wp[(n * 2 + 0) * 64 + lane];
      Wl[n] = wp[(n * 2 + 1) * 64 + lane];
    }
  };

  floatx4 acc[2][4];
#pragma unroll
  for (int mt = 0; mt < 2; ++mt)
#pragma unroll
    for (int n = 0; n < 4; ++n) acc[mt][n] = (floatx4){0.f, 0.f, 0.f, 0.f};

  short8 WhB[2][4], WlB[2][4];

  // Prologue issue order (defines the vmcnt queue): D(0)[4], F(0)[8], D(1)[4]
  issue(0, mybuf);
  loadWF(0, WhB[0], WlB[0]);
  issue(1, mybuf + 4096);

#pragma unroll
  for (int c = 0; c < 16; ++c) {
    // Per-iter issue order: F(c+1)[8] (regs, L2), then D(c+2)[4] (LDS DMA).
    if (c + 1 < 16) loadWF(c + 1, WhB[(c + 1) & 1], WlB[(c + 1) & 1]);
    if (c + 2 < 16) issue(c + 2, mybuf + ((c + 2) % 3) * 4096);
    // Queue oldest->newest at this wait (steady state, c<=13):
    //   D(c)4, F(c)8, D(c+1)4, F(c+1)8, D(c+2)4  = 28 outstanding.
    // Need only {D(c), F(c)} drained -> leave 16 in flight: D(c+1) has had
    // ~2 iterations (>HBM latency) to land by the time it's waited on.
    if (c <= 13) {
      asm volatile("s_waitcnt vmcnt(16)" ::: "memory");
    } else if (c == 14) {
      // queue: D(14)4, F(14)8, D(15)4, F(15)8 = 24 -> drain 12 oldest
      asm volatile("s_waitcnt vmcnt(12)" ::: "memory");
    } else {
      // last chunk: drain everything
      asm volatile("s_waitcnt vmcnt(0)" ::: "memory");
    }

    const float* bb = (const float*)(mybuf + (c % 3) * 4096);
    const short8(&Wh)[4] = WhB[c & 1];
    const short8(&Wl)[4] = WlB[c & 1];
#pragma unroll
    for (int mt = 0; mt < 2; ++mt) {
      const int row = mt * 16 + g;           // A: m = lane&15 (token)
      const int ga0 = r4 * 2;                // A: k-groups (lane>>4)*8 .. +7
      floatx4 a0 = *(const floatx4*)(bb + row * 32 + (((ga0 + 0 + row) & 7) << 2));
      floatx4 a1 = *(const floatx4*)(bb + row * 32 + (((ga0 + 1 + row) & 7) << 2));
      short8 Ah, Al;
#pragma unroll
      for (int j = 0; j < 4; ++j) {
        short h = bf16bits(a0[j]);
        Ah[j] = h; Al[j] = bf16bits(a0[j] - bf16tof(h));
      }
#pragma unroll
      for (int j = 0; j < 4; ++j) {
        short h = bf16bits(a1[j]);
        Ah[4 + j] = h; Al[4 + j] = bf16bits(a1[j] - bf16tof(h));
      }
#pragma unroll
      for (int n = 0; n < 4; ++n) {
        acc[mt][n] = __builtin_amdgcn_mfma_f32_16x16x32_bf16(Ah, Wh[n], acc[mt][n], 0, 0, 0);
        acc[mt][n] = __builtin_amdgcn_mfma_f32_16x16x32_bf16(Ah, Wl[n], acc[mt][n], 0, 0, 0);
        acc[mt][n] = __builtin_amdgcn_mfma_f32_16x16x32_bf16(Al, Wh[n], acc[mt][n], 0, 0, 0);
      }
    }
  }

  // ---- cross-wave K reduction (stride 65: 2-way bank aliasing, free) ----
  __syncthreads();                 // all waves done with stage buffers
  float* red = (float*)smem;
#pragma unroll
  for (int mt = 0; mt < 2; ++mt)
#pragma unroll
    for (int n = 0; n < 4; ++n)
#pragma unroll
      for (int r = 0; r < 4; ++r) {
        const int tokl = mt * 16 + r4 * 4 + r;   // C/D: row = (lane>>4)*4+reg
        const int e = n * 16 + g;                // C/D: col = lane&15
        red[(kq * 32 + tokl) * 65 + e] = acc[mt][n][r];
      }
  __syncthreads();

  // ---- softmax + top-2: token t = kq*8 + (lane&7), experts (lane>>3)*8.. ----
  {
    const int tl = lane & 7, er = lane >> 3;
    const int t = kq * 8 + tl;
    float lv[8];
    float v1 = -INFINITY, v2 = -INFINITY;
    int i1 = 0, i2 = 0;
#pragma unroll
    for (int i = 0; i < 8; ++i) {
      const int e = er * 8 + i;
      float v = red[t * 65 + e] + red[(32 + t) * 65 + e] +
                red[(64 + t) * 65 + e] + red[(96 + t) * 65 + e] + b[e];
      lv[i] = v;
      if (v > v1) { v2 = v1; i2 = i1; v1 = v; i1 = e; }
      else if (v > v2) { v2 = v; i2 = e; }
    }
    // merge top-2 across the 8 expert-lanes (ties -> lowest index)
#pragma unroll
    for (int off = 8; off < 64; off <<= 1) {
      float ov1 = __shfl_xor(v1, off, 64); int oi1 = __shfl_xor(i1, off, 64);
      float ov2 = __shfl_xor(v2, off, 64); int oi2 = __shfl_xor(i2, off, 64);
      bool aw = (v1 > ov1) || (v1 == ov1 && i1 < oi1);
      float nv1 = aw ? v1 : ov1; int ni1 = aw ? i1 : oi1;
      float c2v = aw ? ov1 : v1; int c2i = aw ? oi1 : i1;
      float w2v = aw ? v2 : ov2; int w2i = aw ? i2 : oi2;
      bool sw = (w2v > c2v) || (w2v == c2v && w2i < c2i);
      v2 = sw ? w2v : c2v; i2 = sw ? w2i : c2i;
      v1 = nv1; i1 = ni1;
    }
    float s = 0.f;
#pragma unroll
    for (int i = 0; i < 8; ++i) s += __expf(lv[i] - v1);
#pragma unroll
    for (int off = 8; off < 64; off <<= 1) s += __shfl_xor(s, off, 64);
    if (er == 0) {
      const int tok = tok0 + t;
      out[tok * 2 + 0] = (float)i1;
      out[tok * 2 + 1] = (float)i2;
      out[ntok * 2 + tok * 2 + 0] = 1.0f / s;
      out[ntok * 2 + tok * 2 + 1] = __expf(v2 - v1) / s;
    }
  }
}

extern "C" void kernel_launch(void* const* d_in, const int* in_sizes, int n_in,
                              void* d_out, int out_size, void* d_ws, size_t ws_size,
                              hipStream_t stream) {
  const float* x = (const float*)d_in[0];
  const float* W = (const float*)d_in[1];
  const float* b = (const float*)d_in[2];
  float* out = (float*)d_out;
  const int ntok = in_sizes[0] / DIM;          // 16384
  short8* wf = (short8*)d_ws;                  // 512 KB of W fragments

  wprep_kernel<<<256, 64, 0, stream>>>(W, wf);
  router_main<<<ntok / 32, 256, 0, stream>>>(x, wf, b, out, ntok);
}